// Round 11
// baseline (222.108 us; speedup 1.0000x reference)
//
#include <hip/hip_runtime.h>
#include <math.h>

// ReRanker v6: 2-kernel pipeline, 4 blocks/CU for cross-block latency hiding.
// Diagnosis r5/r10: 1 block/CU (grid 256) left the memory pipe idle during
// butterflies/barriers -> 78us at only 1.7TB/s. v6 splits each b across 4
// blocks (1024 blocks, 256 thr): K1 streams HBM (norms/outer/ic/s-partials,
// atomicAdd into s_ws), K2 streams L3 re-read (inner = (dot(c,s)*ic-1)/(C-1)).
// inner via Gram factorization: sum_k cos(c,k) = dot(chat_c, sum_k chat_k).

#define EPS 1e-8f
constexpr int B = 256;
constexpr int C = 128;
constexpr int D = 1024;
constexpr int QB = 4;              // blocks per b
constexpr int CPB = C / QB;        // 32 candidates per block
constexpr int NW = 4;              // waves per block (256 thr)
constexpr int CPW = CPB / NW;      // 8 candidates per wave

__device__ __forceinline__ float dot4(const float4 a, const float4 b) {
    return a.x * b.x + a.y * b.y + a.z * b.z + a.w * b.w;
}

// K1: per-(b,quarter) block. Pure-stream pairwise pass over 32 cand rows.
__global__ __launch_bounds__(256) void k1_stream(
    const float* __restrict__ doc, const float* __restrict__ summ,
    const float* __restrict__ cand, float* __restrict__ out_outer,
    float* __restrict__ out_sumscore, float* __restrict__ out_sumavg,
    float* __restrict__ ic_ws, float* __restrict__ s_ws) {
    const int blk = blockIdx.x;
    const int b = blk >> 2;
    const int q4 = blk & 3;
    const int t = threadIdx.x;
    const int wave = t >> 6;
    const int lane = t & 63;

    __shared__ float4 dmd[D / 4];      // 4 KiB doc row
    __shared__ float4 dms[D / 4];      // 4 KiB summ row
    __shared__ float s_part[NW][D];    // 16 KiB per-wave weighted col sums
    __shared__ float sa_l[NW];

    dmd[t] = ((const float4*)(doc + (size_t)b * D))[t];
    dms[t] = ((const float4*)(summ + (size_t)b * D))[t];
#pragma unroll
    for (int j = 0; j < 4; ++j)
        ((float4*)s_part[wave])[lane + 64 * j] = make_float4(0.f, 0.f, 0.f, 0.f);
    __syncthreads();

    // doc/summ norms (wave-uniform via butterfly)
    float dd = 0.0f, ss = 0.0f, sd = 0.0f;
#pragma unroll
    for (int j = 0; j < 4; ++j) {
        const float4 d = dmd[lane + 64 * j];
        const float4 m = dms[lane + 64 * j];
        dd += dot4(d, d);
        ss += dot4(m, m);
        sd += dot4(m, d);
    }
#pragma unroll
    for (int lv = 1; lv <= 32; lv <<= 1) {
        dd += __shfl_xor(dd, lv, 64);
        ss += __shfl_xor(ss, lv, 64);
        sd += __shfl_xor(sd, lv, 64);
    }
    const float di = 1.0f / fmaxf(sqrtf(dd), EPS);
    const float si = 1.0f / fmaxf(sqrtf(ss), EPS);
    if (q4 == 0 && t == 0) out_sumscore[b] = sd * di * si;

    const float4* cb = (const float4*)(cand + (size_t)b * C * D);
    float* sw = s_part[wave];
    float sa_acc = 0.0f;

#pragma unroll
    for (int p = 0; p < CPW / 2; ++p) {
        const int c0 = q4 * CPB + wave * CPW + 2 * p;
        const float4* cp0 = cb + (size_t)c0 * (D / 4);
        const float4* cp1 = cp0 + (D / 4);
        float4 cv0[4], cv1[4];
#pragma unroll
        for (int j = 0; j < 4; ++j) {
            cv0[j] = cp0[lane + 64 * j];
            cv1[j] = cp1[lane + 64 * j];
        }
        float cc0 = 0.f, cd0 = 0.f, cs0 = 0.f;
        float cc1 = 0.f, cd1 = 0.f, cs1 = 0.f;
#pragma unroll
        for (int j = 0; j < 4; ++j) {
            const float4 d = dmd[lane + 64 * j];
            const float4 m = dms[lane + 64 * j];
            cc0 += dot4(cv0[j], cv0[j]);
            cd0 += dot4(cv0[j], d);
            cs0 += dot4(cv0[j], m);
            cc1 += dot4(cv1[j], cv1[j]);
            cd1 += dot4(cv1[j], d);
            cs1 += dot4(cv1[j], m);
        }
#pragma unroll
        for (int lv = 1; lv <= 32; lv <<= 1) {
            cc0 += __shfl_xor(cc0, lv, 64);
            cd0 += __shfl_xor(cd0, lv, 64);
            cs0 += __shfl_xor(cs0, lv, 64);
            cc1 += __shfl_xor(cc1, lv, 64);
            cd1 += __shfl_xor(cd1, lv, 64);
            cs1 += __shfl_xor(cs1, lv, 64);
        }
        const float icv0 = 1.0f / fmaxf(sqrtf(cc0), EPS);
        const float icv1 = 1.0f / fmaxf(sqrtf(cc1), EPS);
        sa_acc += cs0 * icv0 + cs1 * icv1;
        if (lane == 0) {
            out_outer[b * C + c0] = cd0 * icv0 * di;
            out_outer[b * C + c0 + 1] = cd1 * icv1 * di;
            ic_ws[b * C + c0] = icv0;
            ic_ws[b * C + c0 + 1] = icv1;
        }
#pragma unroll
        for (int j = 0; j < 4; ++j) {
            float4 cur = ((float4*)sw)[lane + 64 * j];
            cur.x += cv0[j].x * icv0 + cv1[j].x * icv1;
            cur.y += cv0[j].y * icv0 + cv1[j].y * icv1;
            cur.z += cv0[j].z * icv0 + cv1[j].z * icv1;
            cur.w += cv0[j].w * icv0 + cv1[j].w * icv1;
            ((float4*)sw)[lane + 64 * j] = cur;
        }
    }
    if (lane == 0) sa_l[wave] = sa_acc;
    __syncthreads();

    // column-reduce the 4 wave partials, atomicAdd into s_ws[b]
    float* sb = s_ws + (size_t)b * D;
#pragma unroll
    for (int j = 0; j < 4; ++j) {
        const int col = t + 256 * j;
        const float v =
            s_part[0][col] + s_part[1][col] + s_part[2][col] + s_part[3][col];
        atomicAdd(&sb[col], v);
    }
    if (t == 0)
        atomicAdd(&out_sumavg[b],
                  (sa_l[0] + sa_l[1] + sa_l[2] + sa_l[3]) * si * (1.0f / C));
}

// K2: per-(b,quarter) block. L3-hot re-read: inner = (dot(c,s)*ic-1)/(C-1).
__global__ __launch_bounds__(256) void k2_inner(
    const float* __restrict__ cand, const float* __restrict__ s_ws,
    const float* __restrict__ ic_ws, float* __restrict__ out_inner) {
    const int blk = blockIdx.x;
    const int b = blk >> 2;
    const int q4 = blk & 3;
    const int t = threadIdx.x;
    const int wave = t >> 6;
    const int lane = t & 63;

    __shared__ float4 sl[D / 4];  // 4 KiB s row
    sl[t] = ((const float4*)(s_ws + (size_t)b * D))[t];
    __syncthreads();

    const float4* cb = (const float4*)(cand + (size_t)b * C * D);
#pragma unroll
    for (int p = 0; p < CPW / 2; ++p) {
        const int c0 = q4 * CPB + wave * CPW + 2 * p;
        const float4* cp0 = cb + (size_t)c0 * (D / 4);
        const float4* cp1 = cp0 + (D / 4);
        float td0 = 0.f, td1 = 0.f;
#pragma unroll
        for (int j = 0; j < 4; ++j) {
            const float4 sv = sl[lane + 64 * j];
            td0 += dot4(cp0[lane + 64 * j], sv);
            td1 += dot4(cp1[lane + 64 * j], sv);
        }
#pragma unroll
        for (int lv = 1; lv <= 32; lv <<= 1) {
            td0 += __shfl_xor(td0, lv, 64);
            td1 += __shfl_xor(td1, lv, 64);
        }
        if (lane == 0) {
            out_inner[b * C + c0] =
                (td0 * ic_ws[b * C + c0] - 1.0f) * (1.0f / (C - 1));
            out_inner[b * C + c0 + 1] =
                (td1 * ic_ws[b * C + c0 + 1] - 1.0f) * (1.0f / (C - 1));
        }
    }
}

extern "C" void kernel_launch(void* const* d_in, const int* in_sizes, int n_in,
                              void* d_out, int out_size, void* d_ws,
                              size_t ws_size, hipStream_t stream) {
    const float* doc = (const float*)d_in[0];   // [B, D]
    const float* summ = (const float*)d_in[1];  // [B, D]
    const float* cand = (const float*)d_in[2];  // [B, C, D]

    float* out = (float*)d_out;
    float* out_outer = out;                    // [B*C]
    float* out_inner = out + B * C;            // [B*C]
    float* out_sumscore = out + 2 * B * C;     // [B]
    float* out_sumavg = out + 2 * B * C + B;   // [B]

    float* ws = (float*)d_ws;
    float* s_ws = ws;                 // B*D  (1 MiB)
    float* ic_ws = ws + B * D;        // B*C  (128 KiB)

    // zero the atomic accumulators (ws and out are re-poisoned before timing)
    hipMemsetAsync(s_ws, 0, (size_t)B * D * sizeof(float), stream);
    hipMemsetAsync(out_sumavg, 0, B * sizeof(float), stream);

    k1_stream<<<B * QB, 256, 0, stream>>>(doc, summ, cand, out_outer,
                                          out_sumscore, out_sumavg, ic_ws,
                                          s_ws);
    k2_inner<<<B * QB, 256, 0, stream>>>(cand, s_ws, ic_ws, out_inner);
}